// Round 21
// baseline (178.978 us; speedup 1.0000x reference)
//
#include <hip/hip_runtime.h>
#include <hip/hip_fp16.h>

#define NN 100000
#define NE 3200000
#define DF 128
#define HID 32
#define NC 2
#define NBUK 782    // buckets of 128 nodes; bucket = dst >> 7 (782*128 = 100096)
#define CAP 5376    // per-bucket capacity (mean 4092, sigma 64 -> +20 sigma)
#define PEB 8192    // edges per k_part block (391 blocks)

typedef float floatx2 __attribute__((ext_vector_type(2)));

// ---- fp8 e4m3 conversion: HW builtins (gfx950 OCP) with software fallback ----
#if defined(__has_builtin)
#if __has_builtin(__builtin_amdgcn_cvt_pk_fp8_f32) && __has_builtin(__builtin_amdgcn_cvt_pk_f32_fp8)
#define HW_FP8 1
#endif
#endif
#ifndef HW_FP8
#define HW_FP8 0
#endif

#if !HW_FP8
__device__ inline float4 e4m3x4_f4(unsigned u) {
    unsigned w0 = ((u & 0x7fu) << 7) | ((u & 0x80u) << 8)
                | ((u & 0x7f00u) << 15) | ((u & 0x8000u) << 16);
    unsigned t = u >> 16;
    unsigned w1 = ((t & 0x7fu) << 7) | ((t & 0x80u) << 8)
                | ((t & 0x7f00u) << 15) | ((t & 0x8000u) << 16);
    __half2 h0 = *reinterpret_cast<__half2*>(&w0);
    __half2 h1 = *reinterpret_cast<__half2*>(&w1);
    __half2 k = __float2half2_rn(256.f);
    float2 f0 = __half22float2(__hmul2(h0, k));
    float2 f1 = __half22float2(__hmul2(h1, k));
    return make_float4(f0.x, f0.y, f1.x, f1.y);
}
__device__ inline unsigned f2e4m3(float f) {
    unsigned u = __float_as_uint(f);
    unsigned s = (u >> 24) & 0x80u;
    int e = (int)((u >> 23) & 0xffu);
    unsigned m = u & 0x7fffffu;
    int ee = e - 120;
    if (ee >= 16) return s | 0x7eu;
    if (ee <= 0) {
        int sh = 21 - ee;
        if (sh > 31) return s;
        unsigned q = ((0x800000u | m) + (1u << (sh - 1))) >> sh;
        return s | q;
    }
    unsigned q = (m + 0x80000u) >> 20;
    if (q == 8u) { q = 0u; if (++ee >= 16) return s | 0x7eu; }
    if (ee == 15 && q == 7u) return s | 0x7eu;
    return s | ((unsigned)ee << 3) | q;
}
#endif

__device__ inline unsigned pk4_fp8(float a, float b, float c, float d) {
#if HW_FP8
    int w = 0;
    w = __builtin_amdgcn_cvt_pk_fp8_f32(a, b, w, false);  // bytes 0,1
    w = __builtin_amdgcn_cvt_pk_fp8_f32(c, d, w, true);   // bytes 2,3
    return (unsigned)w;
#else
    return f2e4m3(a) | (f2e4m3(b) << 8) | (f2e4m3(c) << 16) | (f2e4m3(d) << 24);
#endif
}

__global__ void k_zc(int* __restrict__ cursor) {
    int i = threadIdx.x;
    if (i < NBUK) cursor[i] = i * CAP;
}

// partition edges into fixed-capacity bucket regions. 1024 threads (16 waves/block).
// LDS-sort by bucket, 16-lane-group coalesced run emission.
// packed word = src | (dst&127)<<17
__global__ __launch_bounds__(1024) void k_part(const int* __restrict__ eidx,
                                               int* __restrict__ cursor,
                                               unsigned* __restrict__ scr) {
    __shared__ unsigned hist[NBUK];
    __shared__ unsigned lofs[NBUK + 1];
    __shared__ unsigned aux[NBUK];
    __shared__ unsigned stage[PEB];      // 32 KB
    __shared__ int sm[1024];
    int tid = threadIdx.x;
    int base = blockIdx.x * PEB;

    if (tid < NBUK) hist[tid] = 0u;
    __syncthreads();

    int s[PEB / 1024], d[PEB / 1024];
#pragma unroll
    for (int i = 0; i < PEB / 1024; ++i) {
        int e = base + i * 1024 + tid;
        if (e < NE) {
            s[i] = eidx[e];
            d[i] = eidx[NE + e];
            atomicAdd(&hist[d[i] >> 7], 1u);
        } else d[i] = -1;
    }
    __syncthreads();

    int v = (tid < NBUK) ? (int)hist[tid] : 0;
    sm[tid] = v;
    __syncthreads();
    for (int off = 1; off < 1024; off <<= 1) {
        int t = (tid >= off) ? sm[tid - off] : 0;
        __syncthreads();
        sm[tid] += t;
        __syncthreads();
    }
    if (tid < NBUK) {
        unsigned excl = (unsigned)(sm[tid] - v);
        lofs[tid] = excl;
        aux[tid] = excl;
    }
    if (tid == 1023) lofs[NBUK] = (unsigned)sm[1023];
    __syncthreads();

#pragma unroll
    for (int i = 0; i < PEB / 1024; ++i) {
        if (d[i] >= 0) {
            unsigned lpos = atomicAdd(&aux[d[i] >> 7], 1u);
            stage[lpos] = (unsigned)s[i] | ((unsigned)(d[i] & 127) << 17);
        }
    }
    __syncthreads();

    if (tid < NBUK) {
        unsigned c = hist[tid];
        hist[tid] = c ? (unsigned)atomicAdd(&cursor[tid], (int)c) : 0u;
    }
    __syncthreads();

    int grp = tid >> 4, lane = tid & 15;
    for (int i = grp; i < NBUK; i += 64) {
        unsigned lo = lofs[i];
        unsigned n = lofs[i + 1] - lo;
        unsigned gbase = hist[i];
        for (unsigned k = lane; k < n; k += 16)
            scr[gbase + k] = stage[lo + k];
    }
}

// per-bucket degree histogram -> dis (needed before gemm1's prescale)
__global__ __launch_bounds__(256) void k_dis(const unsigned* __restrict__ scr,
                                             const int* __restrict__ cursor,
                                             float* __restrict__ dis) {
    int b = blockIdx.x;
    int cs = b * CAP, ce = cursor[b];
    __shared__ unsigned h[128];
    if (threadIdx.x < 128) h[threadIdx.x] = 0u;
    __syncthreads();
    for (int j = cs + threadIdx.x; j < ce; j += 256)
        atomicAdd(&h[(scr[j] >> 17) & 127u], 1u);
    __syncthreads();
    int r = b * 128 + threadIdx.x;
    if (threadIdx.x < 128 && r < NN)
        dis[r] = rsqrtf((float)(h[threadIdx.x] + 1u));  // +1 = self-loop
}

// h1 = dis[r] * (x @ W1), FP8 e4m3 [NN,32].
// Register-tiled LDS GEMM: block = 128 rows x 32 ch, K chunked x4.
// - x staged COALESCED into xs[128][36] (18.4 KB) -> x read exactly once,
//   killing the 512B-strided lane loads that stalled r16-r20 at ~40-78us.
// - W1 chunk transposed into w1t[32][36] (4.6 KB).
// - 4x4 register tile/thread: per k-quad 8 LDS float4 reads for 64 FMA
//   (16 FMA/read). Pad 36 -> x-side conflict-free, 16B-aligned f4 reads.
// Grid 782 x 4 waves = 3128 waves, LDS 23KB -> no grid starvation.
__global__ __launch_bounds__(256) void k_gemm1(const float* __restrict__ x,
                                               const float* __restrict__ dis,
                                               const float* __restrict__ W1,
                                               unsigned* __restrict__ h1) {
    __shared__ __align__(16) float xs[128][36];
    __shared__ __align__(16) float w1t[32][36];
    int tid = threadIdx.x;
    int r0 = blockIdx.x * 128;
    int rt = tid >> 3, ct = tid & 7;   // 32 row-tiles x 8 ch-tiles
    float acc[4][4];
#pragma unroll
    for (int rr = 0; rr < 4; ++rr)
#pragma unroll
        for (int cc = 0; cc < 4; ++cc) acc[rr][cc] = 0.f;

    for (int kc = 0; kc < 4; ++kc) {
        __syncthreads();   // previous chunk's reads complete before overwrite
        // stage x chunk: 128 rows x 32 k, fully coalesced (128B runs)
#pragma unroll
        for (int i = 0; i < 16; ++i) {
            int idx = tid + i * 256;
            int row = idx >> 5, col = idx & 31;
            int gr = r0 + row;
            xs[row][col] = (gr < NN) ? x[(size_t)gr * DF + kc * 32 + col] : 0.f;
        }
        // stage W1 chunk transposed: w1t[ch][k]
#pragma unroll
        for (int i = 0; i < 4; ++i) {
            int idx = tid + i * 256;
            int k = idx >> 5, c = idx & 31;
            w1t[c][k] = W1[(size_t)(kc * 32 + k) * HID + c];
        }
        __syncthreads();
#pragma unroll
        for (int j = 0; j < 8; ++j) {
            float4 xq[4], wq[4];
#pragma unroll
            for (int rr = 0; rr < 4; ++rr)
                xq[rr] = *reinterpret_cast<const float4*>(&xs[rt * 4 + rr][j * 4]);
#pragma unroll
            for (int cc = 0; cc < 4; ++cc)
                wq[cc] = *reinterpret_cast<const float4*>(&w1t[ct * 4 + cc][j * 4]);
#pragma unroll
            for (int rr = 0; rr < 4; ++rr)
#pragma unroll
                for (int cc = 0; cc < 4; ++cc)
                    acc[rr][cc] += xq[rr].x * wq[cc].x + xq[rr].y * wq[cc].y
                                 + xq[rr].z * wq[cc].z + xq[rr].w * wq[cc].w;
        }
    }
    // epilogue: scale by dis[row], pack 4 fp8 ch per row, store u32
#pragma unroll
    for (int rr = 0; rr < 4; ++rr) {
        int rg = r0 + rt * 4 + rr;
        if (rg < NN) {
            float dr = dis[rg];
            unsigned wpk = pk4_fp8(acc[rr][0] * dr, acc[rr][1] * dr,
                                   acc[rr][2] * dr, acc[rr][3] * dr);
            h1[(size_t)rg * 8 + ct] = wpk;
        }
    }
}

// FUSED build + gather1: one block per 128-node bucket.
// pass1 hist; scan -> offsets/dis; pass2 node-sorted LDS scatter; csr writeback;
// gather fp8 rows (32B, L2-resident); +b1/relu/@W2 -> h2 (prescaled).
__global__ __launch_bounds__(512) void k_g1(unsigned* __restrict__ scr,
                                            const int* __restrict__ cursor,
                                            int* __restrict__ rofs, int* __restrict__ rend,
                                            const unsigned* __restrict__ h1,
                                            const float* __restrict__ b1,
                                            const float* __restrict__ W2,
                                            float* __restrict__ h2) {
    int b = blockIdx.x;
    int cs = b * CAP, ce = cursor[b];
    int n = ce - cs;
    __shared__ unsigned stage[CAP];   // 21.5 KB, node-sorted src indices
    __shared__ unsigned cnt[128];
    __shared__ int sm[128];
    __shared__ unsigned ofs[129];
    __shared__ float sd[128];
    int tid = threadIdx.x;

    if (tid < 128) cnt[tid] = 0u;
    __syncthreads();
    for (int j = tid; j < n; j += 512)
        atomicAdd(&cnt[(scr[cs + j] >> 17) & 127u], 1u);
    __syncthreads();
    int v = 0;
    if (tid < 128) { v = (int)cnt[tid]; sm[tid] = v; }
    __syncthreads();
    for (int off = 1; off < 128; off <<= 1) {
        int t = 0;
        if (tid < 128 && tid >= off) t = sm[tid - off];
        __syncthreads();
        if (tid < 128) sm[tid] += t;
        __syncthreads();
    }
    if (tid < 128) {
        int excl = sm[tid] - v;
        ofs[tid] = (unsigned)excl;
        cnt[tid] = (unsigned)excl;
        sd[tid] = rsqrtf((float)(v + 1));     // +1 = self-loop
        if (tid == 127) ofs[128] = (unsigned)(excl + v);
        int node = b * 128 + tid;
        if (node < NN) {
            rofs[node] = cs + excl;
            rend[node] = cs + excl + v;
        }
    }
    __syncthreads();
    for (int j = tid; j < n; j += 512) {
        unsigned w = scr[cs + j];
        unsigned pos = atomicAdd(&cnt[(w >> 17) & 127u], 1u);
        stage[pos] = w & 0x1FFFFu;
    }
    __syncthreads();
    for (int j = tid; j < n; j += 512) scr[cs + j] = stage[j];

    // gather: 4 lanes/node x 128 nodes; lane p reads 8B (channels 8p..8p+7)
    const uint2* hv = reinterpret_cast<const uint2*>(h1);
    int p = tid & 3;
    int rl = tid >> 2;
    int st = (int)ofs[rl], en = (int)ofs[rl + 1];
    float a[8];
#pragma unroll
    for (int k = 0; k < 8; ++k) a[k] = 0.f;

#if HW_FP8
#define ACC8(q)                                                               \
    {                                                                         \
        floatx2 f0 = __builtin_amdgcn_cvt_pk_f32_fp8((int)(q).x, false);      \
        floatx2 f1 = __builtin_amdgcn_cvt_pk_f32_fp8((int)(q).x, true);       \
        floatx2 f2 = __builtin_amdgcn_cvt_pk_f32_fp8((int)(q).y, false);      \
        floatx2 f3 = __builtin_amdgcn_cvt_pk_f32_fp8((int)(q).y, true);       \
        a[0] += f0.x; a[1] += f0.y; a[2] += f1.x; a[3] += f1.y;               \
        a[4] += f2.x; a[5] += f2.y; a[6] += f3.x; a[7] += f3.y;               \
    }
#else
#define ACC8(q)                                                               \
    {                                                                         \
        float4 f0 = e4m3x4_f4((q).x);                                         \
        float4 f1 = e4m3x4_f4((q).y);                                         \
        a[0] += f0.x; a[1] += f0.y; a[2] += f0.z; a[3] += f0.w;               \
        a[4] += f1.x; a[5] += f1.y; a[6] += f1.z; a[7] += f1.w;               \
    }
#endif
    int j = st;
    for (; j + 7 < en; j += 8) {
        unsigned s0 = stage[j], s1 = stage[j + 1], s2 = stage[j + 2], s3 = stage[j + 3];
        unsigned s4 = stage[j + 4], s5 = stage[j + 5], s6 = stage[j + 6], s7 = stage[j + 7];
        uint2 q0 = hv[(size_t)s0 * 4 + p];
        uint2 q1 = hv[(size_t)s1 * 4 + p];
        uint2 q2 = hv[(size_t)s2 * 4 + p];
        uint2 q3 = hv[(size_t)s3 * 4 + p];
        uint2 q4 = hv[(size_t)s4 * 4 + p];
        uint2 q5 = hv[(size_t)s5 * 4 + p];
        uint2 q6 = hv[(size_t)s6 * 4 + p];
        uint2 q7 = hv[(size_t)s7 * 4 + p];
        ACC8(q0) ACC8(q1) ACC8(q2) ACC8(q3)
        ACC8(q4) ACC8(q5) ACC8(q6) ACC8(q7)
    }
    for (; j < en; ++j) {
        uint2 q0 = hv[(size_t)stage[j] * 4 + p];
        ACC8(q0)
    }
    int rg = b * 128 + rl;
    if (rg < NN) {
        uint2 qs = hv[(size_t)rg * 4 + p];   // self term (prescaled)
        ACC8(qs)
        float dr = sd[rl];
        int c = p * 8;
        float4 bl = *reinterpret_cast<const float4*>(b1 + c);
        float4 bh = *reinterpret_cast<const float4*>(b1 + c + 4);
        float vv[8];
        vv[0] = fmaxf(dr * a[0] + bl.x, 0.f); vv[1] = fmaxf(dr * a[1] + bl.y, 0.f);
        vv[2] = fmaxf(dr * a[2] + bl.z, 0.f); vv[3] = fmaxf(dr * a[3] + bl.w, 0.f);
        vv[4] = fmaxf(dr * a[4] + bh.x, 0.f); vv[5] = fmaxf(dr * a[5] + bh.y, 0.f);
        vv[6] = fmaxf(dr * a[6] + bh.z, 0.f); vv[7] = fmaxf(dr * a[7] + bh.w, 0.f);
        float o0 = 0.f, o1 = 0.f;
#pragma unroll
        for (int k = 0; k < 8; ++k) {
            o0 += vv[k] * W2[(c + k) * NC + 0];
            o1 += vv[k] * W2[(c + k) * NC + 1];
        }
        o0 += __shfl_xor(o0, 1); o1 += __shfl_xor(o1, 1);
        o0 += __shfl_xor(o0, 2); o1 += __shfl_xor(o1, 2);
        if (p == 0) {
            h2[2 * (size_t)rg + 0] = dr * o0;   // prescale for layer 2
            h2[2 * (size_t)rg + 1] = dr * o1;
        }
    }
#undef ACC8
}

// gather-aggregate layer 2 (h2 prescaled) + log_softmax -> out
__global__ void k_gather2(const int* __restrict__ rofs, const int* __restrict__ rend,
                          const int* __restrict__ csr, const float* __restrict__ dis,
                          const float* __restrict__ h2, const float* __restrict__ b2,
                          float* __restrict__ out) {
    int r = blockIdx.x * blockDim.x + threadIdx.x;
    if (r >= NN) return;
    int start = rofs[r], end = rend[r];
    float a0 = 0.f, a1 = 0.f;
    int j = start;
    for (; j + 3 < end; j += 4) {
        int s0 = csr[j], s1 = csr[j + 1], s2 = csr[j + 2], s3 = csr[j + 3];
        float2 v0 = *(const float2*)(h2 + 2 * (size_t)s0);
        float2 v1 = *(const float2*)(h2 + 2 * (size_t)s1);
        float2 v2 = *(const float2*)(h2 + 2 * (size_t)s2);
        float2 v3 = *(const float2*)(h2 + 2 * (size_t)s3);
        a0 += v0.x + v1.x + v2.x + v3.x;
        a1 += v0.y + v1.y + v2.y + v3.y;
    }
    for (; j < end; ++j) {
        float2 v = *(const float2*)(h2 + 2 * (size_t)csr[j]);
        a0 += v.x;
        a1 += v.y;
    }
    float dr = dis[r];
    float2 own = *(const float2*)(h2 + 2 * (size_t)r);
    float l0 = dr * (a0 + own.x) + b2[0];
    float l1 = dr * (a1 + own.y) + b2[1];
    float m = fmaxf(l0, l1);
    float lse = m + logf(expf(l0 - m) + expf(l1 - m));
    out[2 * (size_t)r + 0] = l0 - lse;
    out[2 * (size_t)r + 1] = l1 - lse;
}

extern "C" void kernel_launch(void* const* d_in, const int* in_sizes, int n_in,
                              void* d_out, int out_size, void* d_ws, size_t ws_size,
                              hipStream_t stream) {
    const float* x  = (const float*)d_in[0];
    const int* ei   = (const int*)d_in[1];   // [2, NE] int32
    const float* W1 = (const float*)d_in[2];
    const float* b1 = (const float*)d_in[3];
    const float* W2 = (const float*)d_in[4];
    const float* b2 = (const float*)d_in[5];
    float* out      = (float*)d_out;

    float* ws     = (float*)d_ws;
    float* dis    = ws;
    int* rofs     = (int*)(ws + (size_t)NN);
    int* rend     = (int*)(ws + (size_t)2 * NN);
    int* cursor   = (int*)(ws + (size_t)3 * NN);
    float* h2     = ws + (size_t)3 * NN + 800;
    unsigned* h1  = (unsigned*)(ws + (size_t)5 * NN + 800);
    unsigned* scr = (unsigned*)(ws + (size_t)13 * NN + 800);  // -> csr in place

    k_zc<<<1, 1024, 0, stream>>>(cursor);
    k_part<<<(NE + PEB - 1) / PEB, 1024, 0, stream>>>(ei, cursor, scr);
    k_dis<<<NBUK, 256, 0, stream>>>(scr, cursor, dis);
    k_gemm1<<<(NN + 127) / 128, 256, 0, stream>>>(x, dis, W1, h1);
    k_g1<<<NBUK, 512, 0, stream>>>(scr, cursor, rofs, rend, h1, b1, W2, h2);
    k_gather2<<<(NN + 255) / 256, 256, 0, stream>>>(rofs, rend, (const int*)scr, dis, h2, b2, out);
}

// Round 22
// 132.810 us; speedup vs baseline: 1.3476x; 1.3476x over previous
//
#include <hip/hip_runtime.h>
#include <hip/hip_fp16.h>

#define NN 100000
#define NE 3200000
#define DF 128
#define HID 32
#define NC 2
#define NBUK 782    // buckets of 128 nodes; bucket = dst >> 7 (782*128 = 100096)
#define CAP 5376    // per-bucket capacity (mean 4092, sigma 64 -> +20 sigma)
#define PEB 8192    // edges per k_part block (391 blocks)

typedef float floatx2 __attribute__((ext_vector_type(2)));

// ---- fp8 e4m3 conversion: HW builtins (gfx950 OCP) with software fallback ----
#if defined(__has_builtin)
#if __has_builtin(__builtin_amdgcn_cvt_pk_fp8_f32) && __has_builtin(__builtin_amdgcn_cvt_pk_f32_fp8)
#define HW_FP8 1
#endif
#endif
#ifndef HW_FP8
#define HW_FP8 0
#endif

#if !HW_FP8
__device__ inline float4 e4m3x4_f4(unsigned u) {
    unsigned w0 = ((u & 0x7fu) << 7) | ((u & 0x80u) << 8)
                | ((u & 0x7f00u) << 15) | ((u & 0x8000u) << 16);
    unsigned t = u >> 16;
    unsigned w1 = ((t & 0x7fu) << 7) | ((t & 0x80u) << 8)
                | ((t & 0x7f00u) << 15) | ((t & 0x8000u) << 16);
    __half2 h0 = *reinterpret_cast<__half2*>(&w0);
    __half2 h1 = *reinterpret_cast<__half2*>(&w1);
    __half2 k = __float2half2_rn(256.f);
    float2 f0 = __half22float2(__hmul2(h0, k));
    float2 f1 = __half22float2(__hmul2(h1, k));
    return make_float4(f0.x, f0.y, f1.x, f1.y);
}
__device__ inline unsigned f2e4m3(float f) {
    unsigned u = __float_as_uint(f);
    unsigned s = (u >> 24) & 0x80u;
    int e = (int)((u >> 23) & 0xffu);
    unsigned m = u & 0x7fffffu;
    int ee = e - 120;
    if (ee >= 16) return s | 0x7eu;
    if (ee <= 0) {
        int sh = 21 - ee;
        if (sh > 31) return s;
        unsigned q = ((0x800000u | m) + (1u << (sh - 1))) >> sh;
        return s | q;
    }
    unsigned q = (m + 0x80000u) >> 20;
    if (q == 8u) { q = 0u; if (++ee >= 16) return s | 0x7eu; }
    if (ee == 15 && q == 7u) return s | 0x7eu;
    return s | ((unsigned)ee << 3) | q;
}
#endif

__device__ inline unsigned pk4_fp8(float a, float b, float c, float d) {
#if HW_FP8
    int w = 0;
    w = __builtin_amdgcn_cvt_pk_fp8_f32(a, b, w, false);  // bytes 0,1
    w = __builtin_amdgcn_cvt_pk_fp8_f32(c, d, w, true);   // bytes 2,3
    return (unsigned)w;
#else
    return f2e4m3(a) | (f2e4m3(b) << 8) | (f2e4m3(c) << 16) | (f2e4m3(d) << 24);
#endif
}

__global__ void k_zc(int* __restrict__ cursor) {
    int i = threadIdx.x;
    if (i < NBUK) cursor[i] = i * CAP;
}

// partition edges into fixed-capacity bucket regions. 1024 threads (16 waves/block).
// LDS-sort by bucket, 16-lane-group coalesced run emission.
// packed word = src | (dst&127)<<17
__global__ __launch_bounds__(1024) void k_part(const int* __restrict__ eidx,
                                               int* __restrict__ cursor,
                                               unsigned* __restrict__ scr) {
    __shared__ unsigned hist[NBUK];
    __shared__ unsigned lofs[NBUK + 1];
    __shared__ unsigned aux[NBUK];
    __shared__ unsigned stage[PEB];      // 32 KB
    __shared__ int sm[1024];
    int tid = threadIdx.x;
    int base = blockIdx.x * PEB;

    if (tid < NBUK) hist[tid] = 0u;
    __syncthreads();

    int s[PEB / 1024], d[PEB / 1024];
#pragma unroll
    for (int i = 0; i < PEB / 1024; ++i) {
        int e = base + i * 1024 + tid;
        if (e < NE) {
            s[i] = eidx[e];
            d[i] = eidx[NE + e];
            atomicAdd(&hist[d[i] >> 7], 1u);
        } else d[i] = -1;
    }
    __syncthreads();

    int v = (tid < NBUK) ? (int)hist[tid] : 0;
    sm[tid] = v;
    __syncthreads();
    for (int off = 1; off < 1024; off <<= 1) {
        int t = (tid >= off) ? sm[tid - off] : 0;
        __syncthreads();
        sm[tid] += t;
        __syncthreads();
    }
    if (tid < NBUK) {
        unsigned excl = (unsigned)(sm[tid] - v);
        lofs[tid] = excl;
        aux[tid] = excl;
    }
    if (tid == 1023) lofs[NBUK] = (unsigned)sm[1023];
    __syncthreads();

#pragma unroll
    for (int i = 0; i < PEB / 1024; ++i) {
        if (d[i] >= 0) {
            unsigned lpos = atomicAdd(&aux[d[i] >> 7], 1u);
            stage[lpos] = (unsigned)s[i] | ((unsigned)(d[i] & 127) << 17);
        }
    }
    __syncthreads();

    if (tid < NBUK) {
        unsigned c = hist[tid];
        hist[tid] = c ? (unsigned)atomicAdd(&cursor[tid], (int)c) : 0u;
    }
    __syncthreads();

    int grp = tid >> 4, lane = tid & 15;
    for (int i = grp; i < NBUK; i += 64) {
        unsigned lo = lofs[i];
        unsigned n = lofs[i + 1] - lo;
        unsigned gbase = hist[i];
        for (unsigned k = lane; k < n; k += 16)
            scr[gbase + k] = stage[lo + k];
    }
}

// per-bucket degree histogram -> dis (needed before gemm1's prescale)
__global__ __launch_bounds__(256) void k_dis(const unsigned* __restrict__ scr,
                                             const int* __restrict__ cursor,
                                             float* __restrict__ dis) {
    int b = blockIdx.x;
    int cs = b * CAP, ce = cursor[b];
    __shared__ unsigned h[128];
    if (threadIdx.x < 128) h[threadIdx.x] = 0u;
    __syncthreads();
    for (int j = cs + threadIdx.x; j < ce; j += 256)
        atomicAdd(&h[(scr[j] >> 17) & 127u], 1u);
    __syncthreads();
    int r = b * 128 + threadIdx.x;
    if (threadIdx.x < 128 && r < NN)
        dis[r] = rsqrtf((float)(h[threadIdx.x] + 1u));  // +1 = self-loop
}

// h1 = dis[r] * (x @ W1), FP8 e4m3 [NN,32]. 1 thread/row (r16 structure: 39.8us).
// NEW: asm register-pin on each loaded x chunk. r16/r18 showed VGPR=24 -> the
// compiler re-tiled the channel loop and re-read x 4x from L3 (the 30us excess).
// "+v" makes xq values asm-outputs: the compiler CANNOT re-materialize them by
// re-loading, so x is read from global EXACTLY once. W1 stays wave-uniform scalar.
__global__ __launch_bounds__(256) void k_gemm1(const float* __restrict__ x,
                                               const float* __restrict__ dis,
                                               const float* __restrict__ W1,
                                               unsigned* __restrict__ h1) {
    int r = blockIdx.x * blockDim.x + threadIdx.x;
    if (r >= NN) return;
    const float4* xr = reinterpret_cast<const float4*>(x + (size_t)r * DF);
    float acc[HID];
#pragma unroll
    for (int c = 0; c < HID; ++c) acc[c] = 0.f;
#pragma unroll
    for (int kc = 0; kc < 4; ++kc) {
        float4 xq[8];
#pragma unroll
        for (int j = 0; j < 8; ++j) xq[j] = xr[kc * 8 + j];
        // pin loaded values into registers (anti-rematerialization fence)
#pragma unroll
        for (int j = 0; j < 8; ++j)
            asm volatile("" : "+v"(xq[j].x), "+v"(xq[j].y), "+v"(xq[j].z), "+v"(xq[j].w));
#pragma unroll
        for (int j = 0; j < 8; ++j) {
            const float* wb = W1 + (size_t)(kc * 32 + j * 4) * HID;   // wave-uniform
#pragma unroll
            for (int c = 0; c < HID; ++c) {
                acc[c] += xq[j].x * wb[c];
                acc[c] += xq[j].y * wb[HID + c];
                acc[c] += xq[j].z * wb[2 * HID + c];
                acc[c] += xq[j].w * wb[3 * HID + c];
            }
        }
    }
    float dr = dis[r];
    unsigned w[8];
#pragma unroll
    for (int j = 0; j < 8; ++j)
        w[j] = pk4_fp8(acc[4 * j] * dr, acc[4 * j + 1] * dr,
                       acc[4 * j + 2] * dr, acc[4 * j + 3] * dr);
    uint4* dst = reinterpret_cast<uint4*>(h1 + (size_t)r * 8);
    dst[0] = make_uint4(w[0], w[1], w[2], w[3]);
    dst[1] = make_uint4(w[4], w[5], w[6], w[7]);
}

// FUSED build + gather1: one block per 128-node bucket.
// pass1 hist; scan -> offsets/dis; pass2 node-sorted LDS scatter; csr writeback;
// gather fp8 rows (32B, L2-resident); +b1/relu/@W2 -> h2 (prescaled).
__global__ __launch_bounds__(512) void k_g1(unsigned* __restrict__ scr,
                                            const int* __restrict__ cursor,
                                            int* __restrict__ rofs, int* __restrict__ rend,
                                            const unsigned* __restrict__ h1,
                                            const float* __restrict__ b1,
                                            const float* __restrict__ W2,
                                            float* __restrict__ h2) {
    int b = blockIdx.x;
    int cs = b * CAP, ce = cursor[b];
    int n = ce - cs;
    __shared__ unsigned stage[CAP];   // 21.5 KB, node-sorted src indices
    __shared__ unsigned cnt[128];
    __shared__ int sm[128];
    __shared__ unsigned ofs[129];
    __shared__ float sd[128];
    int tid = threadIdx.x;

    if (tid < 128) cnt[tid] = 0u;
    __syncthreads();
    for (int j = tid; j < n; j += 512)
        atomicAdd(&cnt[(scr[cs + j] >> 17) & 127u], 1u);
    __syncthreads();
    int v = 0;
    if (tid < 128) { v = (int)cnt[tid]; sm[tid] = v; }
    __syncthreads();
    for (int off = 1; off < 128; off <<= 1) {
        int t = 0;
        if (tid < 128 && tid >= off) t = sm[tid - off];
        __syncthreads();
        if (tid < 128) sm[tid] += t;
        __syncthreads();
    }
    if (tid < 128) {
        int excl = sm[tid] - v;
        ofs[tid] = (unsigned)excl;
        cnt[tid] = (unsigned)excl;
        sd[tid] = rsqrtf((float)(v + 1));     // +1 = self-loop
        if (tid == 127) ofs[128] = (unsigned)(excl + v);
        int node = b * 128 + tid;
        if (node < NN) {
            rofs[node] = cs + excl;
            rend[node] = cs + excl + v;
        }
    }
    __syncthreads();
    for (int j = tid; j < n; j += 512) {
        unsigned w = scr[cs + j];
        unsigned pos = atomicAdd(&cnt[(w >> 17) & 127u], 1u);
        stage[pos] = w & 0x1FFFFu;
    }
    __syncthreads();
    for (int j = tid; j < n; j += 512) scr[cs + j] = stage[j];

    // gather: 4 lanes/node x 128 nodes; lane p reads 8B (channels 8p..8p+7)
    const uint2* hv = reinterpret_cast<const uint2*>(h1);
    int p = tid & 3;
    int rl = tid >> 2;
    int st = (int)ofs[rl], en = (int)ofs[rl + 1];
    float a[8];
#pragma unroll
    for (int k = 0; k < 8; ++k) a[k] = 0.f;

#if HW_FP8
#define ACC8(q)                                                               \
    {                                                                         \
        floatx2 f0 = __builtin_amdgcn_cvt_pk_f32_fp8((int)(q).x, false);      \
        floatx2 f1 = __builtin_amdgcn_cvt_pk_f32_fp8((int)(q).x, true);       \
        floatx2 f2 = __builtin_amdgcn_cvt_pk_f32_fp8((int)(q).y, false);      \
        floatx2 f3 = __builtin_amdgcn_cvt_pk_f32_fp8((int)(q).y, true);       \
        a[0] += f0.x; a[1] += f0.y; a[2] += f1.x; a[3] += f1.y;               \
        a[4] += f2.x; a[5] += f2.y; a[6] += f3.x; a[7] += f3.y;               \
    }
#else
#define ACC8(q)                                                               \
    {                                                                         \
        float4 f0 = e4m3x4_f4((q).x);                                         \
        float4 f1 = e4m3x4_f4((q).y);                                         \
        a[0] += f0.x; a[1] += f0.y; a[2] += f0.z; a[3] += f0.w;               \
        a[4] += f1.x; a[5] += f1.y; a[6] += f1.z; a[7] += f1.w;               \
    }
#endif
    int j = st;
    for (; j + 7 < en; j += 8) {
        unsigned s0 = stage[j], s1 = stage[j + 1], s2 = stage[j + 2], s3 = stage[j + 3];
        unsigned s4 = stage[j + 4], s5 = stage[j + 5], s6 = stage[j + 6], s7 = stage[j + 7];
        uint2 q0 = hv[(size_t)s0 * 4 + p];
        uint2 q1 = hv[(size_t)s1 * 4 + p];
        uint2 q2 = hv[(size_t)s2 * 4 + p];
        uint2 q3 = hv[(size_t)s3 * 4 + p];
        uint2 q4 = hv[(size_t)s4 * 4 + p];
        uint2 q5 = hv[(size_t)s5 * 4 + p];
        uint2 q6 = hv[(size_t)s6 * 4 + p];
        uint2 q7 = hv[(size_t)s7 * 4 + p];
        ACC8(q0) ACC8(q1) ACC8(q2) ACC8(q3)
        ACC8(q4) ACC8(q5) ACC8(q6) ACC8(q7)
    }
    for (; j < en; ++j) {
        uint2 q0 = hv[(size_t)stage[j] * 4 + p];
        ACC8(q0)
    }
    int rg = b * 128 + rl;
    if (rg < NN) {
        uint2 qs = hv[(size_t)rg * 4 + p];   // self term (prescaled)
        ACC8(qs)
        float dr = sd[rl];
        int c = p * 8;
        float4 bl = *reinterpret_cast<const float4*>(b1 + c);
        float4 bh = *reinterpret_cast<const float4*>(b1 + c + 4);
        float vv[8];
        vv[0] = fmaxf(dr * a[0] + bl.x, 0.f); vv[1] = fmaxf(dr * a[1] + bl.y, 0.f);
        vv[2] = fmaxf(dr * a[2] + bl.z, 0.f); vv[3] = fmaxf(dr * a[3] + bl.w, 0.f);
        vv[4] = fmaxf(dr * a[4] + bh.x, 0.f); vv[5] = fmaxf(dr * a[5] + bh.y, 0.f);
        vv[6] = fmaxf(dr * a[6] + bh.z, 0.f); vv[7] = fmaxf(dr * a[7] + bh.w, 0.f);
        float o0 = 0.f, o1 = 0.f;
#pragma unroll
        for (int k = 0; k < 8; ++k) {
            o0 += vv[k] * W2[(c + k) * NC + 0];
            o1 += vv[k] * W2[(c + k) * NC + 1];
        }
        o0 += __shfl_xor(o0, 1); o1 += __shfl_xor(o1, 1);
        o0 += __shfl_xor(o0, 2); o1 += __shfl_xor(o1, 2);
        if (p == 0) {
            h2[2 * (size_t)rg + 0] = dr * o0;   // prescale for layer 2
            h2[2 * (size_t)rg + 1] = dr * o1;
        }
    }
#undef ACC8
}

// gather-aggregate layer 2 (h2 prescaled) + log_softmax -> out
__global__ void k_gather2(const int* __restrict__ rofs, const int* __restrict__ rend,
                          const int* __restrict__ csr, const float* __restrict__ dis,
                          const float* __restrict__ h2, const float* __restrict__ b2,
                          float* __restrict__ out) {
    int r = blockIdx.x * blockDim.x + threadIdx.x;
    if (r >= NN) return;
    int start = rofs[r], end = rend[r];
    float a0 = 0.f, a1 = 0.f;
    int j = start;
    for (; j + 3 < end; j += 4) {
        int s0 = csr[j], s1 = csr[j + 1], s2 = csr[j + 2], s3 = csr[j + 3];
        float2 v0 = *(const float2*)(h2 + 2 * (size_t)s0);
        float2 v1 = *(const float2*)(h2 + 2 * (size_t)s1);
        float2 v2 = *(const float2*)(h2 + 2 * (size_t)s2);
        float2 v3 = *(const float2*)(h2 + 2 * (size_t)s3);
        a0 += v0.x + v1.x + v2.x + v3.x;
        a1 += v0.y + v1.y + v2.y + v3.y;
    }
    for (; j < end; ++j) {
        float2 v = *(const float2*)(h2 + 2 * (size_t)csr[j]);
        a0 += v.x;
        a1 += v.y;
    }
    float dr = dis[r];
    float2 own = *(const float2*)(h2 + 2 * (size_t)r);
    float l0 = dr * (a0 + own.x) + b2[0];
    float l1 = dr * (a1 + own.y) + b2[1];
    float m = fmaxf(l0, l1);
    float lse = m + logf(expf(l0 - m) + expf(l1 - m));
    out[2 * (size_t)r + 0] = l0 - lse;
    out[2 * (size_t)r + 1] = l1 - lse;
}

extern "C" void kernel_launch(void* const* d_in, const int* in_sizes, int n_in,
                              void* d_out, int out_size, void* d_ws, size_t ws_size,
                              hipStream_t stream) {
    const float* x  = (const float*)d_in[0];
    const int* ei   = (const int*)d_in[1];   // [2, NE] int32
    const float* W1 = (const float*)d_in[2];
    const float* b1 = (const float*)d_in[3];
    const float* W2 = (const float*)d_in[4];
    const float* b2 = (const float*)d_in[5];
    float* out      = (float*)d_out;

    float* ws     = (float*)d_ws;
    float* dis    = ws;
    int* rofs     = (int*)(ws + (size_t)NN);
    int* rend     = (int*)(ws + (size_t)2 * NN);
    int* cursor   = (int*)(ws + (size_t)3 * NN);
    float* h2     = ws + (size_t)3 * NN + 800;
    unsigned* h1  = (unsigned*)(ws + (size_t)5 * NN + 800);
    unsigned* scr = (unsigned*)(ws + (size_t)13 * NN + 800);  // -> csr in place

    k_zc<<<1, 1024, 0, stream>>>(cursor);
    k_part<<<(NE + PEB - 1) / PEB, 1024, 0, stream>>>(ei, cursor, scr);
    k_dis<<<NBUK, 256, 0, stream>>>(scr, cursor, dis);
    k_gemm1<<<(NN + 255) / 256, 256, 0, stream>>>(x, dis, W1, h1);
    k_g1<<<NBUK, 512, 0, stream>>>(scr, cursor, rofs, rend, h1, b1, W2, h2);
    k_gather2<<<(NN + 255) / 256, 256, 0, stream>>>(rofs, rend, (const int*)scr, dis, h2, b2, out);
}

// Round 23
// 99.457 us; speedup vs baseline: 1.7995x; 1.3353x over previous
//
#include <hip/hip_runtime.h>
#include <hip/hip_fp16.h>

#define NN 100000
#define NE 3200000
#define DF 128
#define HID 32
#define NC 2
#define NBUK 782    // buckets of 128 nodes; bucket = dst >> 7 (782*128 = 100096)
#define CAP 5376    // per-bucket capacity (mean 4092, sigma 64 -> +20 sigma)
#define PEB 8192    // edges per k_part block (391 blocks)

typedef float floatx2 __attribute__((ext_vector_type(2)));
typedef short short8v __attribute__((ext_vector_type(8)));   // 8 bf16 = 4 VGPRs
typedef float f32x4 __attribute__((ext_vector_type(4)));

// ---- fp8 e4m3 conversion: HW builtins (gfx950 OCP) with software fallback ----
#if defined(__has_builtin)
#if __has_builtin(__builtin_amdgcn_cvt_pk_fp8_f32) && __has_builtin(__builtin_amdgcn_cvt_pk_f32_fp8)
#define HW_FP8 1
#endif
#endif
#ifndef HW_FP8
#define HW_FP8 0
#endif

#if !HW_FP8
__device__ inline float4 e4m3x4_f4(unsigned u) {
    unsigned w0 = ((u & 0x7fu) << 7) | ((u & 0x80u) << 8)
                | ((u & 0x7f00u) << 15) | ((u & 0x8000u) << 16);
    unsigned t = u >> 16;
    unsigned w1 = ((t & 0x7fu) << 7) | ((t & 0x80u) << 8)
                | ((t & 0x7f00u) << 15) | ((t & 0x8000u) << 16);
    __half2 h0 = *reinterpret_cast<__half2*>(&w0);
    __half2 h1 = *reinterpret_cast<__half2*>(&w1);
    __half2 k = __float2half2_rn(256.f);
    float2 f0 = __half22float2(__hmul2(h0, k));
    float2 f1 = __half22float2(__hmul2(h1, k));
    return make_float4(f0.x, f0.y, f1.x, f1.y);
}
__device__ inline unsigned f2e4m3(float f) {
    unsigned u = __float_as_uint(f);
    unsigned s = (u >> 24) & 0x80u;
    int e = (int)((u >> 23) & 0xffu);
    unsigned m = u & 0x7fffffu;
    int ee = e - 120;
    if (ee >= 16) return s | 0x7eu;
    if (ee <= 0) {
        int sh = 21 - ee;
        if (sh > 31) return s;
        unsigned q = ((0x800000u | m) + (1u << (sh - 1))) >> sh;
        return s | q;
    }
    unsigned q = (m + 0x80000u) >> 20;
    if (q == 8u) { q = 0u; if (++ee >= 16) return s | 0x7eu; }
    if (ee == 15 && q == 7u) return s | 0x7eu;
    return s | ((unsigned)ee << 3) | q;
}
#endif

__device__ inline unsigned pk4_fp8(float a, float b, float c, float d) {
#if HW_FP8
    int w = 0;
    w = __builtin_amdgcn_cvt_pk_fp8_f32(a, b, w, false);  // bytes 0,1
    w = __builtin_amdgcn_cvt_pk_fp8_f32(c, d, w, true);   // bytes 2,3
    return (unsigned)w;
#else
    return f2e4m3(a) | (f2e4m3(b) << 8) | (f2e4m3(c) << 16) | (f2e4m3(d) << 24);
#endif
}

// float -> bf16 (RNE)
__device__ inline short f2bf(float f) {
    unsigned u = __float_as_uint(f);
    return (short)((u + 0x7fffu + ((u >> 16) & 1u)) >> 16);
}

__global__ void k_zc(int* __restrict__ cursor) {
    int i = threadIdx.x;
    if (i < NBUK) cursor[i] = i * CAP;
}

// partition edges into fixed-capacity bucket regions. 1024 threads (16 waves/block).
// LDS-sort by bucket, 16-lane-group coalesced run emission.
// packed word = src | (dst&127)<<17
__global__ __launch_bounds__(1024) void k_part(const int* __restrict__ eidx,
                                               int* __restrict__ cursor,
                                               unsigned* __restrict__ scr) {
    __shared__ unsigned hist[NBUK];
    __shared__ unsigned lofs[NBUK + 1];
    __shared__ unsigned aux[NBUK];
    __shared__ unsigned stage[PEB];      // 32 KB
    __shared__ int sm[1024];
    int tid = threadIdx.x;
    int base = blockIdx.x * PEB;

    if (tid < NBUK) hist[tid] = 0u;
    __syncthreads();

    int s[PEB / 1024], d[PEB / 1024];
#pragma unroll
    for (int i = 0; i < PEB / 1024; ++i) {
        int e = base + i * 1024 + tid;
        if (e < NE) {
            s[i] = eidx[e];
            d[i] = eidx[NE + e];
            atomicAdd(&hist[d[i] >> 7], 1u);
        } else d[i] = -1;
    }
    __syncthreads();

    int v = (tid < NBUK) ? (int)hist[tid] : 0;
    sm[tid] = v;
    __syncthreads();
    for (int off = 1; off < 1024; off <<= 1) {
        int t = (tid >= off) ? sm[tid - off] : 0;
        __syncthreads();
        sm[tid] += t;
        __syncthreads();
    }
    if (tid < NBUK) {
        unsigned excl = (unsigned)(sm[tid] - v);
        lofs[tid] = excl;
        aux[tid] = excl;
    }
    if (tid == 1023) lofs[NBUK] = (unsigned)sm[1023];
    __syncthreads();

#pragma unroll
    for (int i = 0; i < PEB / 1024; ++i) {
        if (d[i] >= 0) {
            unsigned lpos = atomicAdd(&aux[d[i] >> 7], 1u);
            stage[lpos] = (unsigned)s[i] | ((unsigned)(d[i] & 127) << 17);
        }
    }
    __syncthreads();

    if (tid < NBUK) {
        unsigned c = hist[tid];
        hist[tid] = c ? (unsigned)atomicAdd(&cursor[tid], (int)c) : 0u;
    }
    __syncthreads();

    int grp = tid >> 4, lane = tid & 15;
    for (int i = grp; i < NBUK; i += 64) {
        unsigned lo = lofs[i];
        unsigned n = lofs[i + 1] - lo;
        unsigned gbase = hist[i];
        for (unsigned k = lane; k < n; k += 16)
            scr[gbase + k] = stage[lo + k];
    }
}

// per-bucket degree histogram -> dis (needed before gemm1's prescale)
__global__ __launch_bounds__(256) void k_dis(const unsigned* __restrict__ scr,
                                             const int* __restrict__ cursor,
                                             float* __restrict__ dis) {
    int b = blockIdx.x;
    int cs = b * CAP, ce = cursor[b];
    __shared__ unsigned h[128];
    if (threadIdx.x < 128) h[threadIdx.x] = 0u;
    __syncthreads();
    for (int j = cs + threadIdx.x; j < ce; j += 256)
        atomicAdd(&h[(scr[j] >> 17) & 127u], 1u);
    __syncthreads();
    int r = b * 128 + threadIdx.x;
    if (threadIdx.x < 128 && r < NN)
        dis[r] = rsqrtf((float)(h[threadIdx.x] + 1u));  // +1 = self-loop
}

// h1 = dis[r] * (x @ W1), FP8 e4m3 [NN,32] via BF16 MFMA 16x16x32.
// Per wave: 16 rows x 32 ch; B (W1, 16KB L1-hot) preloaded as 8 fragments;
// 4 K-steps x 2 N-tiles = 8 MFMA into f32 acc. Fragment layout (guide section 3):
// A[m=lane&15][k=(lane>>4)*8+j], B[k=(lane>>4)*8+j][n=lane&15],
// C/D: n=lane&15, m=(lane>>4)*4+reg. Grid = 1563 blocks x 4 waves = 6252 waves
// (4x the thread-per-row wave count -> no grid starvation); x read once, dense
// 16-row x 128B tiles. LDS repack -> dis prescale -> pk4_fp8 -> coalesced store.
__global__ __launch_bounds__(256) void k_gemm1(const float* __restrict__ x,
                                               const float* __restrict__ dis,
                                               const float* __restrict__ W1,
                                               unsigned* __restrict__ h1) {
    __shared__ float ot[4][16][33];   // per-wave 16x32 out tile, padded (8.4 KB)
    int tid = threadIdx.x;
    int wv = tid >> 6, l = tid & 63;
    int lm = l & 15;        // A row in tile / B-N col / C col
    int lk = l >> 4;        // k-group (0..3)
    int r0 = blockIdx.x * 64 + wv * 16;

    // preload B fragments: W1[k][c], k = s*32 + lk*8 + j, c = t*16 + lm
    short8v bfrag[4][2];
#pragma unroll
    for (int s = 0; s < 4; ++s)
#pragma unroll
        for (int t = 0; t < 2; ++t)
#pragma unroll
            for (int j = 0; j < 8; ++j)
                bfrag[s][t][j] = f2bf(W1[(size_t)(s * 32 + lk * 8 + j) * HID + t * 16 + lm]);

    // A: row r0+lm (clamped; OOB rows computed but never stored)
    int ra = r0 + lm;
    if (ra >= NN) ra = NN - 1;
    const float4* xr = reinterpret_cast<const float4*>(x + (size_t)ra * DF);

    f32x4 acc0 = {0.f, 0.f, 0.f, 0.f}, acc1 = {0.f, 0.f, 0.f, 0.f};
#pragma unroll
    for (int s = 0; s < 4; ++s) {
        float4 q0 = xr[s * 8 + lk * 2];
        float4 q1 = xr[s * 8 + lk * 2 + 1];
        short8v af;
        af[0] = f2bf(q0.x); af[1] = f2bf(q0.y); af[2] = f2bf(q0.z); af[3] = f2bf(q0.w);
        af[4] = f2bf(q1.x); af[5] = f2bf(q1.y); af[6] = f2bf(q1.z); af[7] = f2bf(q1.w);
        acc0 = __builtin_amdgcn_mfma_f32_16x16x32_bf16(af, bfrag[s][0], acc0, 0, 0, 0);
        acc1 = __builtin_amdgcn_mfma_f32_16x16x32_bf16(af, bfrag[s][1], acc1, 0, 0, 0);
    }
    // C/D: lane l reg q -> row lk*4+q, col lm (tile t adds 16t)
#pragma unroll
    for (int q = 0; q < 4; ++q) {
        ot[wv][lk * 4 + q][lm] = acc0[q];
        ot[wv][lk * 4 + q][16 + lm] = acc1[q];
    }
    __syncthreads();
    // store: lane l -> row l>>2, u32-pair (l&3); prescale by dis
    int row = l >> 2, p = l & 3;
    int rg = r0 + row;
    if (rg < NN) {
        float dr = dis[rg];
        const float* pr = &ot[wv][row][p * 8];
        unsigned lo = pk4_fp8(pr[0] * dr, pr[1] * dr, pr[2] * dr, pr[3] * dr);
        unsigned hi = pk4_fp8(pr[4] * dr, pr[5] * dr, pr[6] * dr, pr[7] * dr);
        reinterpret_cast<uint2*>(h1)[(size_t)rg * 4 + p] = make_uint2(lo, hi);
    }
}

// FUSED build + gather1: one block per 128-node bucket.
// pass1 hist; scan -> offsets/dis; pass2 node-sorted LDS scatter; csr writeback;
// gather fp8 rows (32B, L2-resident); +b1/relu/@W2 -> h2 (prescaled).
__global__ __launch_bounds__(512) void k_g1(unsigned* __restrict__ scr,
                                            const int* __restrict__ cursor,
                                            int* __restrict__ rofs, int* __restrict__ rend,
                                            const unsigned* __restrict__ h1,
                                            const float* __restrict__ b1,
                                            const float* __restrict__ W2,
                                            float* __restrict__ h2) {
    int b = blockIdx.x;
    int cs = b * CAP, ce = cursor[b];
    int n = ce - cs;
    __shared__ unsigned stage[CAP];   // 21.5 KB, node-sorted src indices
    __shared__ unsigned cnt[128];
    __shared__ int sm[128];
    __shared__ unsigned ofs[129];
    __shared__ float sd[128];
    int tid = threadIdx.x;

    if (tid < 128) cnt[tid] = 0u;
    __syncthreads();
    for (int j = tid; j < n; j += 512)
        atomicAdd(&cnt[(scr[cs + j] >> 17) & 127u], 1u);
    __syncthreads();
    int v = 0;
    if (tid < 128) { v = (int)cnt[tid]; sm[tid] = v; }
    __syncthreads();
    for (int off = 1; off < 128; off <<= 1) {
        int t = 0;
        if (tid < 128 && tid >= off) t = sm[tid - off];
        __syncthreads();
        if (tid < 128) sm[tid] += t;
        __syncthreads();
    }
    if (tid < 128) {
        int excl = sm[tid] - v;
        ofs[tid] = (unsigned)excl;
        cnt[tid] = (unsigned)excl;
        sd[tid] = rsqrtf((float)(v + 1));     // +1 = self-loop
        if (tid == 127) ofs[128] = (unsigned)(excl + v);
        int node = b * 128 + tid;
        if (node < NN) {
            rofs[node] = cs + excl;
            rend[node] = cs + excl + v;
        }
    }
    __syncthreads();
    for (int j = tid; j < n; j += 512) {
        unsigned w = scr[cs + j];
        unsigned pos = atomicAdd(&cnt[(w >> 17) & 127u], 1u);
        stage[pos] = w & 0x1FFFFu;
    }
    __syncthreads();
    for (int j = tid; j < n; j += 512) scr[cs + j] = stage[j];

    // gather: 4 lanes/node x 128 nodes; lane p reads 8B (channels 8p..8p+7)
    const uint2* hv = reinterpret_cast<const uint2*>(h1);
    int p = tid & 3;
    int rl = tid >> 2;
    int st = (int)ofs[rl], en = (int)ofs[rl + 1];
    float a[8];
#pragma unroll
    for (int k = 0; k < 8; ++k) a[k] = 0.f;

#if HW_FP8
#define ACC8(q)                                                               \
    {                                                                         \
        floatx2 f0 = __builtin_amdgcn_cvt_pk_f32_fp8((int)(q).x, false);      \
        floatx2 f1 = __builtin_amdgcn_cvt_pk_f32_fp8((int)(q).x, true);       \
        floatx2 f2 = __builtin_amdgcn_cvt_pk_f32_fp8((int)(q).y, false);      \
        floatx2 f3 = __builtin_amdgcn_cvt_pk_f32_fp8((int)(q).y, true);       \
        a[0] += f0.x; a[1] += f0.y; a[2] += f1.x; a[3] += f1.y;               \
        a[4] += f2.x; a[5] += f2.y; a[6] += f3.x; a[7] += f3.y;               \
    }
#else
#define ACC8(q)                                                               \
    {                                                                         \
        float4 f0 = e4m3x4_f4((q).x);                                         \
        float4 f1 = e4m3x4_f4((q).y);                                         \
        a[0] += f0.x; a[1] += f0.y; a[2] += f0.z; a[3] += f0.w;               \
        a[4] += f1.x; a[5] += f1.y; a[6] += f1.z; a[7] += f1.w;               \
    }
#endif
    int j = st;
    for (; j + 7 < en; j += 8) {
        unsigned s0 = stage[j], s1 = stage[j + 1], s2 = stage[j + 2], s3 = stage[j + 3];
        unsigned s4 = stage[j + 4], s5 = stage[j + 5], s6 = stage[j + 6], s7 = stage[j + 7];
        uint2 q0 = hv[(size_t)s0 * 4 + p];
        uint2 q1 = hv[(size_t)s1 * 4 + p];
        uint2 q2 = hv[(size_t)s2 * 4 + p];
        uint2 q3 = hv[(size_t)s3 * 4 + p];
        uint2 q4 = hv[(size_t)s4 * 4 + p];
        uint2 q5 = hv[(size_t)s5 * 4 + p];
        uint2 q6 = hv[(size_t)s6 * 4 + p];
        uint2 q7 = hv[(size_t)s7 * 4 + p];
        ACC8(q0) ACC8(q1) ACC8(q2) ACC8(q3)
        ACC8(q4) ACC8(q5) ACC8(q6) ACC8(q7)
    }
    for (; j < en; ++j) {
        uint2 q0 = hv[(size_t)stage[j] * 4 + p];
        ACC8(q0)
    }
    int rg = b * 128 + rl;
    if (rg < NN) {
        uint2 qs = hv[(size_t)rg * 4 + p];   // self term (prescaled)
        ACC8(qs)
        float dr = sd[rl];
        int c = p * 8;
        float4 bl = *reinterpret_cast<const float4*>(b1 + c);
        float4 bh = *reinterpret_cast<const float4*>(b1 + c + 4);
        float vv[8];
        vv[0] = fmaxf(dr * a[0] + bl.x, 0.f); vv[1] = fmaxf(dr * a[1] + bl.y, 0.f);
        vv[2] = fmaxf(dr * a[2] + bl.z, 0.f); vv[3] = fmaxf(dr * a[3] + bl.w, 0.f);
        vv[4] = fmaxf(dr * a[4] + bh.x, 0.f); vv[5] = fmaxf(dr * a[5] + bh.y, 0.f);
        vv[6] = fmaxf(dr * a[6] + bh.z, 0.f); vv[7] = fmaxf(dr * a[7] + bh.w, 0.f);
        float o0 = 0.f, o1 = 0.f;
#pragma unroll
        for (int k = 0; k < 8; ++k) {
            o0 += vv[k] * W2[(c + k) * NC + 0];
            o1 += vv[k] * W2[(c + k) * NC + 1];
        }
        o0 += __shfl_xor(o0, 1); o1 += __shfl_xor(o1, 1);
        o0 += __shfl_xor(o0, 2); o1 += __shfl_xor(o1, 2);
        if (p == 0) {
            h2[2 * (size_t)rg + 0] = dr * o0;   // prescale for layer 2
            h2[2 * (size_t)rg + 1] = dr * o1;
        }
    }
#undef ACC8
}

// gather-aggregate layer 2 (h2 prescaled) + log_softmax -> out
__global__ void k_gather2(const int* __restrict__ rofs, const int* __restrict__ rend,
                          const int* __restrict__ csr, const float* __restrict__ dis,
                          const float* __restrict__ h2, const float* __restrict__ b2,
                          float* __restrict__ out) {
    int r = blockIdx.x * blockDim.x + threadIdx.x;
    if (r >= NN) return;
    int start = rofs[r], end = rend[r];
    float a0 = 0.f, a1 = 0.f;
    int j = start;
    for (; j + 3 < end; j += 4) {
        int s0 = csr[j], s1 = csr[j + 1], s2 = csr[j + 2], s3 = csr[j + 3];
        float2 v0 = *(const float2*)(h2 + 2 * (size_t)s0);
        float2 v1 = *(const float2*)(h2 + 2 * (size_t)s1);
        float2 v2 = *(const float2*)(h2 + 2 * (size_t)s2);
        float2 v3 = *(const float2*)(h2 + 2 * (size_t)s3);
        a0 += v0.x + v1.x + v2.x + v3.x;
        a1 += v0.y + v1.y + v2.y + v3.y;
    }
    for (; j < end; ++j) {
        float2 v = *(const float2*)(h2 + 2 * (size_t)csr[j]);
        a0 += v.x;
        a1 += v.y;
    }
    float dr = dis[r];
    float2 own = *(const float2*)(h2 + 2 * (size_t)r);
    float l0 = dr * (a0 + own.x) + b2[0];
    float l1 = dr * (a1 + own.y) + b2[1];
    float m = fmaxf(l0, l1);
    float lse = m + logf(expf(l0 - m) + expf(l1 - m));
    out[2 * (size_t)r + 0] = l0 - lse;
    out[2 * (size_t)r + 1] = l1 - lse;
}

extern "C" void kernel_launch(void* const* d_in, const int* in_sizes, int n_in,
                              void* d_out, int out_size, void* d_ws, size_t ws_size,
                              hipStream_t stream) {
    const float* x  = (const float*)d_in[0];
    const int* ei   = (const int*)d_in[1];   // [2, NE] int32
    const float* W1 = (const float*)d_in[2];
    const float* b1 = (const float*)d_in[3];
    const float* W2 = (const float*)d_in[4];
    const float* b2 = (const float*)d_in[5];
    float* out      = (float*)d_out;

    float* ws     = (float*)d_ws;
    float* dis    = ws;
    int* rofs     = (int*)(ws + (size_t)NN);
    int* rend     = (int*)(ws + (size_t)2 * NN);
    int* cursor   = (int*)(ws + (size_t)3 * NN);
    float* h2     = ws + (size_t)3 * NN + 800;
    unsigned* h1  = (unsigned*)(ws + (size_t)5 * NN + 800);
    unsigned* scr = (unsigned*)(ws + (size_t)13 * NN + 800);  // -> csr in place

    k_zc<<<1, 1024, 0, stream>>>(cursor);
    k_part<<<(NE + PEB - 1) / PEB, 1024, 0, stream>>>(ei, cursor, scr);
    k_dis<<<NBUK, 256, 0, stream>>>(scr, cursor, dis);
    k_gemm1<<<(NN + 63) / 64, 256, 0, stream>>>(x, dis, W1, h1);
    k_g1<<<NBUK, 512, 0, stream>>>(scr, cursor, rofs, rend, h1, b1, W2, h2);
    k_gather2<<<(NN + 255) / 256, 256, 0, stream>>>(rofs, rend, (const int*)scr, dis, h2, b2, out);
}